// Round 11
// baseline (171.783 us; speedup 1.0000x reference)
//
#include <hip/hip_runtime.h>
#include <hip/hip_bf16.h>
#include <stdint.h>

#define N_NODES 20000
#define N_EDGES 640000
#define FEAT 128
#define CAP8 24    // per-(partition,dst) cap; Pois(4), P(any overflow) ~ 1e-6
#define NPART 8    // XCD-private counter/list partitions (vx = bid & 7)
#define NPHASE 8   // o-feature slices of 16 (2.56 MB h-slice, L2-resident per XCD)

typedef __attribute__((ext_vector_type(8))) short bf16x8;
typedef __attribute__((ext_vector_type(4))) float f32x4;

// ---------- helpers ----------
// packed f32x2 -> bf16x2 (v_cvt_pk_bf16_f32), lo in low half
__device__ __forceinline__ unsigned pkbf16(float lo, float hi) {
  __hip_bfloat162 p = __float22bfloat162_rn(make_float2(lo, hi));
  return *reinterpret_cast<unsigned*>(&p);
}

// order-preserving encode: f32 -> RNE-rounded bf16 -> monotone u16
__device__ __forceinline__ unsigned short enc16(float f) {
  unsigned a = __float_as_uint(f);
  unsigned b = (a + 0x7FFFu + ((a >> 16) & 1u)) >> 16;  // RNE to bf16
  unsigned s = (unsigned)((int)a >> 31);                // 0 or ~0
  return (unsigned short)((b ^ 0x8000u) ^ (s & 0x7FFFu));
}

// inverse of enc16 (result as f32)
__device__ __forceinline__ float dec16(unsigned e) {
  unsigned b = (e & 0x8000u) ? (e ^ 0x8000u) : (e ^ 0xFFFFu);
  return __uint_as_float(b << 16);
}

// packed 2x u16 max
__device__ __forceinline__ void pmax(unsigned& a, unsigned v) {
  asm("v_pk_max_u16 %0, %0, %1" : "+v"(a) : "v"(v));
}

#define PMX4(v)                                              \
  do {                                                       \
    pmax(a0, (v).x); pmax(a1, (v).y);                        \
    pmax(a2, (v).z); pmax(a3, (v).w);                        \
  } while (0)

// ---------- kernel 1: grid-specialized scatter/GEMM, one dispatch ----------
// bid%3==2 -> scatter block, XCD-PRIVATE counters/lists (vx = bid&7): atomics
//             stay in the home XCD's L2 -- no cross-XCD line-ownership
//             migration (the R9/R10 latency wall). Correct for ANY bid->XCD
//             mapping; locality assumes round-robin dispatch.
// bid%3<2  -> pure GEMM block: x and W staged in LDS, 8 waves all MFMA.
__global__ __launch_bounds__(512) void gemm_scatter_kernel(
    const float4* __restrict__ x, const float* __restrict__ W,
    const float* __restrict__ b, uint4* __restrict__ h,
    const int* __restrict__ ei, int* __restrict__ cnt,
    unsigned short* __restrict__ csr) {
  // x-stage: [t][16 n][136 f] = 17408 B (aliased by h-stage [16 n][520] u16).
  // W-stage: [128 o][136 f] bf16 = 34816 B.  Total 52224 B -> 3 blocks/CU.
  __shared__ __align__(16) unsigned short sm[17408 / 2];
  __shared__ __align__(16) unsigned short Wlds[128 * 136];
  const int tid = threadIdx.x;  // 0..511
  const int bid = blockIdx.x;
  const int m3 = bid % 3;

  if (m3 == 2) {
    // ---- scatter block: 1024 edges into partition vx ----
    const int base = (bid / 3) * 1024;
    const int vx = bid & 7;
    int* mycnt = cnt + vx * N_NODES;
    unsigned short* mycsr = csr + (size_t)vx * N_NODES * CAP8;
#pragma unroll
    for (int r = 0; r < 2; ++r) {
      int e = base + r * 512 + tid;
      int src = ei[e];
      int dst = ei[N_EDGES + e];
      int pos = atomicAdd(&mycnt[dst], 1);
      if (pos < CAP8) mycsr[(size_t)dst * CAP8 + pos] = (unsigned short)src;
    }
    return;
  }

  // ---- pure GEMM block ----
  const int tile = (bid / 3) * 2 + m3;  // 0..1249
  const int n0 = tile * 16;

  // stage W -> LDS bf16: thread t converts 32 floats of row o = t>>2
  {
    const float4* Wv = (const float4*)W;
    const int o = tid >> 2;
    const int q0 = (tid & 3) * 8;  // float4 index within row
    float4 wa[8];
#pragma unroll
    for (int q = 0; q < 8; ++q) wa[q] = Wv[o * 32 + q0 + q];
    unsigned* wrow = (unsigned*)&Wlds[o * 136] + (tid & 3) * 16;
#pragma unroll
    for (int q = 0; q < 8; ++q) {
      wrow[2 * q] = pkbf16(wa[q].x, wa[q].y);
      wrow[2 * q + 1] = pkbf16(wa[q].z, wa[q].w);
    }
  }

  // staging loads: 4x float4 per thread (2 f-pair units)
  const int e0 = tid, e1 = tid + 512;
  const int na = e0 >> 6, fa = e0 & 63;
  const int nb = e1 >> 6, fb = e1 & 63;
  float4 a0 = x[(size_t)(n0 + na) * 128 + 2 * fa];
  float4 c0 = x[(size_t)(n0 + na) * 128 + 2 * fa + 1];
  float4 a1 = x[(size_t)(n0 + nb) * 128 + 2 * fb];
  float4 c1 = x[(size_t)(n0 + nb) * 128 + 2 * fb + 1];

  ((unsigned*)sm)[(0 * 16 + na) * 68 + fa] = pkbf16(a0.x, c0.x);
  ((unsigned*)sm)[(1 * 16 + na) * 68 + fa] = pkbf16(a0.y, c0.y);
  ((unsigned*)sm)[(2 * 16 + na) * 68 + fa] = pkbf16(a0.z, c0.z);
  ((unsigned*)sm)[(3 * 16 + na) * 68 + fa] = pkbf16(a0.w, c0.w);
  ((unsigned*)sm)[(0 * 16 + nb) * 68 + fb] = pkbf16(a1.x, c1.x);
  ((unsigned*)sm)[(1 * 16 + nb) * 68 + fb] = pkbf16(a1.y, c1.y);
  ((unsigned*)sm)[(2 * 16 + nb) * 68 + fb] = pkbf16(a1.z, c1.z);
  ((unsigned*)sm)[(3 * 16 + nb) * 68 + fb] = pkbf16(a1.w, c1.w);

  __syncthreads();

  const int wv = tid >> 6;  // 8 waves
  const int l = tid & 63;
  const int col = l & 15;
  const int quad = l >> 4;
  const int t = wv & 3;     // t-slice
  const int osh = wv >> 2;  // os half: 0 -> os 0..3, 1 -> os 4..7

  f32x4 acc[4];
#pragma unroll
  for (int os = 0; os < 4; ++os) {
    float bv = b[(osh * 4 + os) * 16 + col];
    acc[os] = (f32x4){bv, bv, bv, bv};
  }

#pragma unroll
  for (int k = 0; k < 4; ++k) {
    bf16x8 af = *(const bf16x8*)&sm[(t * 16 + col) * 136 + k * 32 + quad * 8];
#pragma unroll
    for (int os = 0; os < 4; ++os) {
      bf16x8 bfv =
          *(const bf16x8*)&Wlds[((osh * 4 + os) * 16 + col) * 136 + k * 32 + quad * 8];
      acc[os] = __builtin_amdgcn_mfma_f32_16x16x32_bf16(af, bfv, acc[os], 0, 0, 0);
    }
  }

  __syncthreads();

  // C layout: D[m = quad*4 + r][o = (osh*4+os)*16 + col]; h-stage [n][o][t], row 520.
#pragma unroll
  for (int os = 0; os < 4; ++os) {
#pragma unroll
    for (int r = 0; r < 4; ++r) {
      sm[(quad * 4 + r) * 520 + ((osh * 4 + os) * 16 + col) * 4 + t] = enc16(acc[os][r]);
    }
  }
  __syncthreads();

  // h-write: 2 uint4 per thread across all 8 waves
#pragma unroll
  for (int it = 0; it < 2; ++it) {
    int e = tid + it * 512;
    int n = e >> 6, q = e & 63;
    uint4 v = *(const uint4*)&sm[n * 520 + q * 8];
    h[(size_t)(n0 + n) * 64 + q] = v;
  }
}

// ---------- kernel 2: o-phased agg, 8 dsts/wave, concat staging, straight ILP-8 ----------
// phase = blockIdx.x & 7 == XCD: 2.56 MB h-slice stays L2-resident per XCD.
// Staging: thread (r = tid>>3, vx = tid&7) copies its partition's bucket into
// the dst's LDS row at an offset from an 8-lane shfl scan. Main loop = proven
// R6 body: one ds_read_b128 of 8 indices + 8 independent dwordx4 gathers.
__global__ __launch_bounds__(256) void agg_kernel(
    const uint4* __restrict__ h, const int* __restrict__ cnt,
    const unsigned short* __restrict__ csr, float4* __restrict__ out) {
  __shared__ __align__(16) unsigned short sidx[32][200];  // 12.5 KB (cap 192 + pad)
  __shared__ int degs[32];
  const int bid = blockIdx.x;  // 5000 blocks = 625 grp x 8 phases
  const int p = bid & 7;
  const int grp = bid >> 3;
  const int n0 = grp * 32;
  const int tid = threadIdx.x;

  // ---- concat staging: (dst r, partition vx) per thread ----
  {
    const int vx = tid & 7;
    const int r = tid >> 3;  // 0..31
    const int nn = n0 + r;
    int c = cnt[vx * N_NODES + nn];
    c = c > CAP8 ? CAP8 : c;
    int s = c;
#pragma unroll
    for (int d = 1; d < 8; d <<= 1) {
      int tt = __shfl_up(s, d, 8);
      if (vx >= d) s += tt;
    }
    int off = s - c;  // exclusive prefix within dst
    if (vx == 7) degs[r] = s;
    const unsigned short* bsrc = csr + ((size_t)vx * N_NODES + nn) * CAP8;
    for (int k = 0; k < c; ++k) sidx[r][off + k] = bsrc[k];
  }
  __syncthreads();

  const int w = tid >> 6;
  const int lane = tid & 63;
  const int g = lane >> 3;       // dst slot within wave
  const int oq = lane & 7;       // o-pair slot (2 o x 4 t = 16 B)
  const int n = n0 + w * 8 + g;  // this lane's dst

  const int deg = degs[w * 8 + g];  // <= 192
  const unsigned short* myrow = sidx[w * 8 + g];
  int idx0 = (deg > 0) ? (int)myrow[0] : 0;  // clamp target (valid & L1-hot)

  // wave-max of deg (uniform loop bound; clamped lanes load dups)
  int dmax = deg;
#pragma unroll
  for (int d = 8; d <= 32; d <<= 1) {
    int o = __shfl_xor(dmax, d);
    dmax = o > dmax ? o : dmax;
  }
  dmax = __builtin_amdgcn_readfirstlane(dmax);

  unsigned a0 = 0x007F007Fu, a1 = a0, a2 = a0, a3 = a0;  // enc(-inf) packed
  const char* hb = (const char*)h;
  const unsigned pb = (((unsigned)p * 8 + oq) << 4);  // byte offset within h row

  for (int jb = 0; jb < dmax; jb += 8) {
    uint4 iv = *(const uint4*)&myrow[jb];  // ds_read_b128: 8 indices, broadcast
    int e0 = (int)(iv.x & 0xFFFFu), e1 = (int)(iv.x >> 16);
    int e2 = (int)(iv.y & 0xFFFFu), e3 = (int)(iv.y >> 16);
    int e4 = (int)(iv.z & 0xFFFFu), e5 = (int)(iv.z >> 16);
    int e6 = (int)(iv.w & 0xFFFFu), e7 = (int)(iv.w >> 16);
    e0 = (jb + 0 < deg) ? e0 : idx0;
    e1 = (jb + 1 < deg) ? e1 : idx0;
    e2 = (jb + 2 < deg) ? e2 : idx0;
    e3 = (jb + 3 < deg) ? e3 : idx0;
    e4 = (jb + 4 < deg) ? e4 : idx0;
    e5 = (jb + 5 < deg) ? e5 : idx0;
    e6 = (jb + 6 < deg) ? e6 : idx0;
    e7 = (jb + 7 < deg) ? e7 : idx0;
    uint4 v0 = *(const uint4*)(hb + (((unsigned)e0 << 10) + pb));
    uint4 v1 = *(const uint4*)(hb + (((unsigned)e1 << 10) + pb));
    uint4 v2 = *(const uint4*)(hb + (((unsigned)e2 << 10) + pb));
    uint4 v3 = *(const uint4*)(hb + (((unsigned)e3 << 10) + pb));
    uint4 v4 = *(const uint4*)(hb + (((unsigned)e4 << 10) + pb));
    uint4 v5 = *(const uint4*)(hb + (((unsigned)e5 << 10) + pb));
    uint4 v6 = *(const uint4*)(hb + (((unsigned)e6 << 10) + pb));
    uint4 v7 = *(const uint4*)(hb + (((unsigned)e7 << 10) + pb));
    PMX4(v0); PMX4(v1); PMX4(v2); PMX4(v3);
    PMX4(v4); PMX4(v5); PMX4(v6); PMX4(v7);
  }

  float4 o0, o1;
  if (deg == 0) {
    o0 = make_float4(0.f, 0.f, 0.f, 0.f);
    o1 = o0;
  } else {
    o0 = make_float4(dec16(a0 & 0xFFFFu), dec16(a0 >> 16),
                     dec16(a1 & 0xFFFFu), dec16(a1 >> 16));
    o1 = make_float4(dec16(a2 & 0xFFFFu), dec16(a2 >> 16),
                     dec16(a3 & 0xFFFFu), dec16(a3 >> 16));
  }
  out[(size_t)n * 128 + p * 16 + oq * 2] = o0;
  out[(size_t)n * 128 + p * 16 + oq * 2 + 1] = o1;
}

// ---------- launcher ----------
extern "C" void kernel_launch(void* const* d_in, const int* in_sizes, int n_in,
                              void* d_out, int out_size, void* d_ws, size_t ws_size,
                              hipStream_t stream) {
  const float* x = (const float*)d_in[0];
  const int* ei = (const int*)d_in[1];
  const float* W = (const float*)d_in[2];
  const float* b = (const float*)d_in[3];
  float* out = (float*)d_out;

  char* ws = (char*)d_ws;
  uint4* h = (uint4*)ws;                                   // 20,480,000 B
  int* cnt = (int*)(ws + 20480000);                        // 8 x 20,000 x 4 = 640,000 B
  unsigned short* csr = (unsigned short*)(ws + 21120000);  // 8*20000*24*2 = 7,680,000 B

  hipMemsetAsync(cnt, 0, NPART * N_NODES * sizeof(int), stream);
  // 1875 blocks: 1250 gemm tiles (bid%3<2) + 625 scatter blocks (bid%3==2)
  gemm_scatter_kernel<<<1875, 512, 0, stream>>>((const float4*)x, W, b, h,
                                                ei, cnt, csr);
  agg_kernel<<<(N_NODES / 32) * NPHASE, 256, 0, stream>>>(h, cnt, csr, (float4*)out);
}

// Round 12
// 164.232 us; speedup vs baseline: 1.0460x; 1.0460x over previous
//
#include <hip/hip_runtime.h>
#include <hip/hip_bf16.h>
#include <stdint.h>

#define N_NODES 20000
#define N_EDGES 640000
#define FEAT 128
#define CAPD 128      // per-dst list cap; deg ~ Poisson(32), P(>128) ~ 1e-43
#define NPHASE 8      // o-feature slices of 16 (2.56 MB h-slice, L2-resident per XCD)
#define CNTSTRIDE 16  // one counter per 64B line

typedef __attribute__((ext_vector_type(8))) short bf16x8;
typedef __attribute__((ext_vector_type(4))) float f32x4;

// ---------- helpers ----------
// packed f32x2 -> bf16x2 (v_cvt_pk_bf16_f32), lo in low half
__device__ __forceinline__ unsigned pkbf16(float lo, float hi) {
  __hip_bfloat162 p = __float22bfloat162_rn(make_float2(lo, hi));
  return *reinterpret_cast<unsigned*>(&p);
}

// order-preserving encode: f32 -> RNE-rounded bf16 -> monotone u16
__device__ __forceinline__ unsigned short enc16(float f) {
  unsigned a = __float_as_uint(f);
  unsigned b = (a + 0x7FFFu + ((a >> 16) & 1u)) >> 16;  // RNE to bf16
  unsigned s = (unsigned)((int)a >> 31);                // 0 or ~0
  return (unsigned short)((b ^ 0x8000u) ^ (s & 0x7FFFu));
}

// inverse of enc16 (result as f32)
__device__ __forceinline__ float dec16(unsigned e) {
  unsigned b = (e & 0x8000u) ? (e ^ 0x8000u) : (e ^ 0xFFFFu);
  return __uint_as_float(b << 16);
}

// packed 2x u16 max
__device__ __forceinline__ void pmax(unsigned& a, unsigned v) {
  asm("v_pk_max_u16 %0, %0, %1" : "+v"(a) : "v"(v));
}

#define PMX4(v)                                              \
  do {                                                       \
    pmax(a0, (v).x); pmax(a1, (v).y);                        \
    pmax(a2, (v).z); pmax(a3, (v).w);                        \
  } while (0)

// ---------- kernel 1: grid-specialized scatter/GEMM (R10 exact) ----------
// bid%3==2 -> pure scatter block: 1024 edges, padded counters, no barriers.
// bid%3<2  -> pure GEMM block: x and W staged in LDS, 8 waves all MFMA.
__global__ __launch_bounds__(512) void gemm_scatter_kernel(
    const float4* __restrict__ x, const float* __restrict__ W,
    const float* __restrict__ b, uint4* __restrict__ h,
    const int* __restrict__ ei, int* __restrict__ cnt,
    unsigned short* __restrict__ csr) {
  // x-stage: [t][16 n][136 f] = 17408 B (aliased by h-stage [16 n][520] u16).
  // W-stage: [128 o][136 f] bf16 = 34816 B.  Total 52224 B -> 3 blocks/CU.
  __shared__ __align__(16) unsigned short sm[17408 / 2];
  __shared__ __align__(16) unsigned short Wlds[128 * 136];
  const int tid = threadIdx.x;  // 0..511
  const int bid = blockIdx.x;
  const int m3 = bid % 3;

  if (m3 == 2) {
    // ---- pure scatter block: 1024 edges ----
    const int base = (bid / 3) * 1024;
#pragma unroll
    for (int r = 0; r < 2; ++r) {
      int e = base + r * 512 + tid;
      int src = ei[e];
      int dst = ei[N_EDGES + e];
      int pos = atomicAdd(&cnt[dst * CNTSTRIDE], 1);
      if (pos < CAPD) csr[(size_t)dst * CAPD + pos] = (unsigned short)src;
    }
    return;
  }

  // ---- pure GEMM block ----
  const int tile = (bid / 3) * 2 + m3;  // 0..1249
  const int n0 = tile * 16;

  // stage W -> LDS bf16: thread t converts 32 floats of row o = t>>2
  {
    const float4* Wv = (const float4*)W;
    const int o = tid >> 2;
    const int q0 = (tid & 3) * 8;  // float4 index within row
    float4 wa[8];
#pragma unroll
    for (int q = 0; q < 8; ++q) wa[q] = Wv[o * 32 + q0 + q];
    unsigned* wrow = (unsigned*)&Wlds[o * 136] + (tid & 3) * 16;
#pragma unroll
    for (int q = 0; q < 8; ++q) {
      wrow[2 * q] = pkbf16(wa[q].x, wa[q].y);
      wrow[2 * q + 1] = pkbf16(wa[q].z, wa[q].w);
    }
  }

  // staging loads: 4x float4 per thread (2 f-pair units)
  const int e0 = tid, e1 = tid + 512;
  const int na = e0 >> 6, fa = e0 & 63;
  const int nb = e1 >> 6, fb = e1 & 63;
  float4 a0 = x[(size_t)(n0 + na) * 128 + 2 * fa];
  float4 c0 = x[(size_t)(n0 + na) * 128 + 2 * fa + 1];
  float4 a1 = x[(size_t)(n0 + nb) * 128 + 2 * fb];
  float4 c1 = x[(size_t)(n0 + nb) * 128 + 2 * fb + 1];

  ((unsigned*)sm)[(0 * 16 + na) * 68 + fa] = pkbf16(a0.x, c0.x);
  ((unsigned*)sm)[(1 * 16 + na) * 68 + fa] = pkbf16(a0.y, c0.y);
  ((unsigned*)sm)[(2 * 16 + na) * 68 + fa] = pkbf16(a0.z, c0.z);
  ((unsigned*)sm)[(3 * 16 + na) * 68 + fa] = pkbf16(a0.w, c0.w);
  ((unsigned*)sm)[(0 * 16 + nb) * 68 + fb] = pkbf16(a1.x, c1.x);
  ((unsigned*)sm)[(1 * 16 + nb) * 68 + fb] = pkbf16(a1.y, c1.y);
  ((unsigned*)sm)[(2 * 16 + nb) * 68 + fb] = pkbf16(a1.z, c1.z);
  ((unsigned*)sm)[(3 * 16 + nb) * 68 + fb] = pkbf16(a1.w, c1.w);

  __syncthreads();

  const int wv = tid >> 6;  // 8 waves
  const int l = tid & 63;
  const int col = l & 15;
  const int quad = l >> 4;
  const int t = wv & 3;     // t-slice
  const int osh = wv >> 2;  // os half: 0 -> os 0..3, 1 -> os 4..7

  f32x4 acc[4];
#pragma unroll
  for (int os = 0; os < 4; ++os) {
    float bv = b[(osh * 4 + os) * 16 + col];
    acc[os] = (f32x4){bv, bv, bv, bv};
  }

#pragma unroll
  for (int k = 0; k < 4; ++k) {
    bf16x8 af = *(const bf16x8*)&sm[(t * 16 + col) * 136 + k * 32 + quad * 8];
#pragma unroll
    for (int os = 0; os < 4; ++os) {
      bf16x8 bfv =
          *(const bf16x8*)&Wlds[((osh * 4 + os) * 16 + col) * 136 + k * 32 + quad * 8];
      acc[os] = __builtin_amdgcn_mfma_f32_16x16x32_bf16(af, bfv, acc[os], 0, 0, 0);
    }
  }

  __syncthreads();

  // C layout: D[m = quad*4 + r][o = (osh*4+os)*16 + col]; h-stage [n][o][t], row 520.
#pragma unroll
  for (int os = 0; os < 4; ++os) {
#pragma unroll
    for (int r = 0; r < 4; ++r) {
      sm[(quad * 4 + r) * 520 + ((osh * 4 + os) * 16 + col) * 4 + t] = enc16(acc[os][r]);
    }
  }
  __syncthreads();

  // h-write: 2 uint4 per thread across all 8 waves
#pragma unroll
  for (int it = 0; it < 2; ++it) {
    int e = tid + it * 512;
    int n = e >> 6, q = e & 63;
    uint4 v = *(const uint4*)&sm[n * 520 + q * 8];
    h[(size_t)(n0 + n) * 64 + q] = v;
  }
}

// ---------- kernel 2: o-phased agg, 8 dsts/wave, dup-free two-regime loop ----------
// phase = blockIdx.x & 7 == XCD: 2.56 MB h-slice stays L2-resident per XCD.
// Lane (g, oq) owns dst g's 16 B o-slice; indices staged in LDS (R6 proven).
// HEAD (jb+8 <= dmin): unmasked batch of 8 loads, no clamps at all.
// TAIL (dmin..dmax): exec-masked loads (pre-set to enc(-inf)) -- masked-off
// lanes issue NO memory op, eliminating the 1.37x dup-gather inflation that
// the old clamp-to-idx0 scheme paid on the L1/L2 return path.
__global__ __launch_bounds__(256) void agg_kernel(
    const uint4* __restrict__ h, const int* __restrict__ cnt,
    const unsigned short* __restrict__ csr, float4* __restrict__ out) {
  __shared__ __align__(16) unsigned short sidx[32][136];  // 8704 B, row-padded
  const int bid = blockIdx.x;  // 5000 blocks = 625 grp x 8 phases
  const int p = bid & 7;
  const int grp = bid >> 3;
  const int n0 = grp * 32;
  const int tid = threadIdx.x;

  // stage 32 csr rows -> LDS (each thread copies 2x uint4 = 32 B, coalesced)
  {
    int r = tid >> 3;  // 0..31
    int q = tid & 7;   // 0..7
    const uint4* srow = (const uint4*)(csr + (size_t)(n0 + r) * CAPD);
    *(uint4*)&sidx[r][q * 8] = srow[q];
    *(uint4*)&sidx[r][(q + 8) * 8] = srow[q + 8];
  }
  __syncthreads();

  const int w = tid >> 6;
  const int lane = tid & 63;
  const int g = lane >> 3;       // dst slot within wave
  const int oq = lane & 7;       // o-pair slot (2 o x 4 t = 16 B)
  const int n = n0 + w * 8 + g;  // this lane's dst

  int deg = cnt[n * CNTSTRIDE];
  deg = deg > CAPD ? CAPD : deg;

  const unsigned short* myrow = sidx[w * 8 + g];

  // wave min & max of deg (uniform loop bounds)
  int dmin = deg, dmax = deg;
#pragma unroll
  for (int d = 8; d <= 32; d <<= 1) {
    int om = __shfl_xor(dmin, d);
    int ox = __shfl_xor(dmax, d);
    dmin = om < dmin ? om : dmin;
    dmax = ox > dmax ? ox : dmax;
  }
  dmin = __builtin_amdgcn_readfirstlane(dmin);
  dmax = __builtin_amdgcn_readfirstlane(dmax);

  unsigned a0 = 0x007F007Fu, a1 = a0, a2 = a0, a3 = a0;  // enc(-inf) packed
  const char* hb = (const char*)h;
  const unsigned pb = (((unsigned)p * 8 + oq) << 4);  // byte offset within h row

  int jb = 0;
  // ---- HEAD: all 8 dsts have >= jb+8 entries -> no clamping, no masking ----
  for (; jb + 8 <= dmin; jb += 8) {
    uint4 iv = *(const uint4*)&myrow[jb];  // ds_read_b128: 8 indices, broadcast
    uint4 v0 = *(const uint4*)(hb + (((unsigned)(iv.x & 0xFFFFu) << 10) + pb));
    uint4 v1 = *(const uint4*)(hb + (((unsigned)(iv.x >> 16) << 10) + pb));
    uint4 v2 = *(const uint4*)(hb + (((unsigned)(iv.y & 0xFFFFu) << 10) + pb));
    uint4 v3 = *(const uint4*)(hb + (((unsigned)(iv.y >> 16) << 10) + pb));
    uint4 v4 = *(const uint4*)(hb + (((unsigned)(iv.z & 0xFFFFu) << 10) + pb));
    uint4 v5 = *(const uint4*)(hb + (((unsigned)(iv.z >> 16) << 10) + pb));
    uint4 v6 = *(const uint4*)(hb + (((unsigned)(iv.w & 0xFFFFu) << 10) + pb));
    uint4 v7 = *(const uint4*)(hb + (((unsigned)(iv.w >> 16) << 10) + pb));
    PMX4(v0); PMX4(v1); PMX4(v2); PMX4(v3);
    PMX4(v4); PMX4(v5); PMX4(v6); PMX4(v7);
  }
  // ---- TAIL: exec-masked loads; inactive lanes issue nothing ----
  for (; jb < dmax; jb += 8) {
    uint4 iv = *(const uint4*)&myrow[jb];
    const uint4 NEG = {0x007F007Fu, 0x007F007Fu, 0x007F007Fu, 0x007F007Fu};
    uint4 v0 = NEG, v1 = NEG, v2 = NEG, v3 = NEG;
    uint4 v4 = NEG, v5 = NEG, v6 = NEG, v7 = NEG;
    if (jb + 0 < deg) v0 = *(const uint4*)(hb + (((unsigned)(iv.x & 0xFFFFu) << 10) + pb));
    if (jb + 1 < deg) v1 = *(const uint4*)(hb + (((unsigned)(iv.x >> 16) << 10) + pb));
    if (jb + 2 < deg) v2 = *(const uint4*)(hb + (((unsigned)(iv.y & 0xFFFFu) << 10) + pb));
    if (jb + 3 < deg) v3 = *(const uint4*)(hb + (((unsigned)(iv.y >> 16) << 10) + pb));
    if (jb + 4 < deg) v4 = *(const uint4*)(hb + (((unsigned)(iv.z & 0xFFFFu) << 10) + pb));
    if (jb + 5 < deg) v5 = *(const uint4*)(hb + (((unsigned)(iv.z >> 16) << 10) + pb));
    if (jb + 6 < deg) v6 = *(const uint4*)(hb + (((unsigned)(iv.w & 0xFFFFu) << 10) + pb));
    if (jb + 7 < deg) v7 = *(const uint4*)(hb + (((unsigned)(iv.w >> 16) << 10) + pb));
    PMX4(v0); PMX4(v1); PMX4(v2); PMX4(v3);
    PMX4(v4); PMX4(v5); PMX4(v6); PMX4(v7);
  }

  float4 o0, o1;
  if (deg == 0) {
    o0 = make_float4(0.f, 0.f, 0.f, 0.f);
    o1 = o0;
  } else {
    o0 = make_float4(dec16(a0 & 0xFFFFu), dec16(a0 >> 16),
                     dec16(a1 & 0xFFFFu), dec16(a1 >> 16));
    o1 = make_float4(dec16(a2 & 0xFFFFu), dec16(a2 >> 16),
                     dec16(a3 & 0xFFFFu), dec16(a3 >> 16));
  }
  out[(size_t)n * 128 + p * 16 + oq * 2] = o0;
  out[(size_t)n * 128 + p * 16 + oq * 2 + 1] = o1;
}

// ---------- launcher ----------
extern "C" void kernel_launch(void* const* d_in, const int* in_sizes, int n_in,
                              void* d_out, int out_size, void* d_ws, size_t ws_size,
                              hipStream_t stream) {
  const float* x = (const float*)d_in[0];
  const int* ei = (const int*)d_in[1];
  const float* W = (const float*)d_in[2];
  const float* b = (const float*)d_in[3];
  float* out = (float*)d_out;

  char* ws = (char*)d_ws;
  uint4* h = (uint4*)ws;                                   // 20,480,000 B
  int* cnt = (int*)(ws + 20480000);                        // 20,000 x 16 x 4 = 1,280,000 B
  unsigned short* csr = (unsigned short*)(ws + 21760000);  // 20000*128*2 = 5,120,000 B

  hipMemsetAsync(cnt, 0, N_NODES * CNTSTRIDE * sizeof(int), stream);
  // 1875 blocks: 1250 gemm tiles (bid%3<2) + 625 scatter blocks (bid%3==2)
  gemm_scatter_kernel<<<1875, 512, 0, stream>>>((const float4*)x, W, b, h,
                                                ei, cnt, csr);
  agg_kernel<<<(N_NODES / 32) * NPHASE, 256, 0, stream>>>(h, cnt, csr, (float4*)out);
}